// Round 4
// baseline (1952.476 us; speedup 1.0000x reference)
//
#include <hip/hip_runtime.h>

// Conv: out = (norm * (x + segment_sum(x[sources], targets))) @ W
// N = 100000, E = 4000000, C = 64, fp32.
// Strategy: bucket targets into 128-node bins (counting sort, coalesced-run
// writes), then per-bucket LDS accumulation (ds_add_f32, zero global fp32
// atomics) with 8-deep-MLP x-row gather, fused scale+matmul epilogue.

constexpr int C = 64;
constexpr int BN = 128;      // nodes per bucket (32 KB LDS agg)
constexpr int CHUNK = 4096;  // edges per binning block
constexpr int MAXB = 1024;   // LDS histogram capacity (NB=782 for N=100000)

// --- 1. global bucket histogram ---------------------------------------------
__global__ __launch_bounds__(256) void hist_kernel(
    const int* __restrict__ tgt, int* __restrict__ ghist, int E, int NB) {
  __shared__ int h[MAXB];
  for (int i = threadIdx.x; i < NB; i += 256) h[i] = 0;
  __syncthreads();
  int base = blockIdx.x * CHUNK;
  int end = base + CHUNK; if (end > E) end = E;
  for (int i = base + threadIdx.x; i < end; i += 256)
    atomicAdd(&h[tgt[i] >> 7], 1);
  __syncthreads();
  for (int i = threadIdx.x; i < NB; i += 256)
    if (h[i]) atomicAdd(&ghist[i], h[i]);
}

// --- 2. exclusive scan of NB bucket counts (1 block) ------------------------
__global__ __launch_bounds__(256) void scan_kernel(
    const int* __restrict__ ghist, int* __restrict__ gbase,
    int* __restrict__ gcursor, int NB) {
  __shared__ int partials[256];
  int tid = threadIdx.x;
  int per = (NB + 255) / 256;
  int lo = tid * per, hi = lo + per;
  if (lo > NB) lo = NB;
  if (hi > NB) hi = NB;
  int s = 0;
  for (int i = lo; i < hi; i++) s += ghist[i];
  partials[tid] = s;
  __syncthreads();
  for (int off = 1; off < 256; off <<= 1) {
    int v = partials[tid];
    int a = (tid >= off) ? partials[tid - off] : 0;
    __syncthreads();
    partials[tid] = v + a;
    __syncthreads();
  }
  int run = partials[tid] - s;
  for (int i = lo; i < hi; i++) {
    gbase[i] = run; gcursor[i] = run; run += ghist[i];
  }
  if (tid == 255) gbase[NB] = partials[255];
}

// --- 3. bin edges: per-block counting sort -> contiguous runs per bucket ----
// Packed record: src (17b) << 7 | (tgt & 127). Writes within a (block,bucket)
// run are dense -> ~1x line amplification (vs 15x for R2's random CSR fill).
__global__ __launch_bounds__(256) void bin_kernel(
    const int* __restrict__ src, const int* __restrict__ tgt,
    int* __restrict__ gcursor, unsigned* __restrict__ recs, int E, int NB) {
  __shared__ unsigned rec[CHUNK];  // 16 KB
  __shared__ int bkt[CHUNK];       // 16 KB
  __shared__ int hist[MAXB];       // 4 KB
  __shared__ int gb[MAXB];         // 4 KB
  int tid = threadIdx.x;
  int base = blockIdx.x * CHUNK;
  int count = E - base; if (count > CHUNK) count = CHUNK;

  for (int i = tid; i < NB; i += 256) hist[i] = 0;
  __syncthreads();
  for (int i = tid; i < count; i += 256) {
    int s = src[base + i], t = tgt[base + i];
    int b = t >> 7;
    rec[i] = ((unsigned)s << 7) | (unsigned)(t & 127);
    bkt[i] = b;
    atomicAdd(&hist[b], 1);
  }
  __syncthreads();
  for (int i = tid; i < NB; i += 256) {
    int c = hist[i];
    gb[i] = c ? atomicAdd(&gcursor[i], c) : 0;
  }
  __syncthreads();
  for (int i = tid; i < NB; i += 256) hist[i] = 0;
  __syncthreads();
  for (int i = tid; i < count; i += 256) {
    int b = bkt[i];
    int idx = atomicAdd(&hist[b], 1);
    recs[gb[b] + idx] = rec[i];
  }
}

// --- 4. per-bucket LDS accumulate + scale + matmul --------------------------
// One block per bucket. agg[128][64] in LDS (32 KB). Records streamed
// coalesced; x-row gathers issued 8-deep per wave for MLP; ds_add_f32
// accumulation (2-way bank aliasing = free). W held in 64 VGPRs per lane.
__global__ __launch_bounds__(256) void acc_kernel(
    const float* __restrict__ x, const unsigned* __restrict__ recs,
    const int* __restrict__ gbase, const float* __restrict__ norm,
    const float* __restrict__ W, float* __restrict__ out, int N) {
  __shared__ float agg[BN * C];  // 32 KB
  int tid = threadIdx.x;
  int lane = tid & 63;
  int wave = tid >> 6;
  int b = blockIdx.x;
  int n0 = b * BN;
  int nn = N - n0; if (nn > BN) nn = BN;

  // W column `lane` into registers (64 VGPRs)
  float wreg[C];
#pragma unroll
  for (int k = 0; k < C; k++) wreg[k] = W[k * C + lane];

  // self term: agg = x rows of this bucket (coalesced)
  for (int i = tid; i < nn * C; i += 256) agg[i] = x[n0 * C + i];
  __syncthreads();

  int beg = gbase[b], end = gbase[b + 1];
  for (int r0 = beg + wave * 64; r0 < end; r0 += 256) {
    int cnt = end - r0; if (cnt > 64) cnt = 64;
    unsigned rc = (lane < cnt) ? recs[r0 + lane] : 0u;
    int j = 0;
    for (; j + 8 <= cnt; j += 8) {
      unsigned q[8]; float v[8];
#pragma unroll
      for (int u = 0; u < 8; u++) q[u] = (unsigned)__shfl((int)rc, j + u, 64);
#pragma unroll
      for (int u = 0; u < 8; u++) v[u] = x[(q[u] >> 7) * C + lane];
#pragma unroll
      for (int u = 0; u < 8; u++)
        atomicAdd(&agg[(q[u] & 127u) * C + lane], v[u]);
    }
    for (; j < cnt; j++) {
      unsigned q = (unsigned)__shfl((int)rc, j, 64);
      atomicAdd(&agg[(q & 127u) * C + lane], x[(q >> 7) * C + lane]);
    }
  }
  __syncthreads();

  // epilogue: wave w owns nodes [w*32, w*32+32) -- no cross-wave reads
  int i0 = wave * 32, i1 = i0 + 32;
  if (i1 > nn) i1 = nn;
  for (int i = i0; i < i1; i++) {
    float nv = norm[n0 + i];
    agg[i * C + lane] *= nv;  // h = norm * (x + sum)
  }
  for (int i = i0; i < i1; i++) {
    const float4* hp = (const float4*)&agg[i * C];
    float o = 0.0f;
#pragma unroll
    for (int k4 = 0; k4 < 16; k4++) {
      float4 h4 = hp[k4];  // all lanes same address -> LDS broadcast
      o = fmaf(h4.x, wreg[k4 * 4 + 0], o);
      o = fmaf(h4.y, wreg[k4 * 4 + 1], o);
      o = fmaf(h4.z, wreg[k4 * 4 + 2], o);
      o = fmaf(h4.w, wreg[k4 * 4 + 3], o);
    }
    out[(n0 + i) * C + lane] = o;
  }
}

extern "C" void kernel_launch(void* const* d_in, const int* in_sizes, int n_in,
                              void* d_out, int out_size, void* d_ws, size_t ws_size,
                              hipStream_t stream) {
  const float* x       = (const float*)d_in[0];
  const int*   sources = (const int*)d_in[1];
  const int*   targets = (const int*)d_in[2];
  const float* norm    = (const float*)d_in[3];
  const float* weight  = (const float*)d_in[4];
  float* out = (float*)d_out;

  int N = in_sizes[0] / C;   // 100000
  int E = in_sizes[1];       // 4000000
  int NB = (N + BN - 1) / BN;  // 782

  // workspace: ghist[NB] | gbase[NB+1] | gcursor[NB] | recs[E]
  int* ghist   = (int*)d_ws;
  int* gbase   = ghist + NB;
  int* gcursor = gbase + (NB + 1);
  unsigned* recs = (unsigned*)(gcursor + NB);

  hipMemsetAsync(ghist, 0, (size_t)NB * sizeof(int), stream);

  int eblocks = (E + CHUNK - 1) / CHUNK;  // 977
  hist_kernel<<<eblocks, 256, 0, stream>>>(targets, ghist, E, NB);
  scan_kernel<<<1, 256, 0, stream>>>(ghist, gbase, gcursor, NB);
  bin_kernel<<<eblocks, 256, 0, stream>>>(sources, targets, gcursor, recs, E, NB);
  acc_kernel<<<NB, 256, 0, stream>>>(x, recs, gbase, norm, weight, out, N);
}

// Round 5
// 727.196 us; speedup vs baseline: 2.6849x; 2.6849x over previous
//
#include <hip/hip_runtime.h>

// Conv: out = (norm * (x + segment_sum(x[sources], targets))) @ W
// N = 100000, E = 4000000, C = 64, fp32.
// Pipeline: node-hist -> scan -> bucket-bin (dense runs) -> bucket counting
// sort to exact CSR (dense writes) -> transposed float4 gather (4 edges per
// load instr, zero atomics, zero LDS in the hot chain) + fused scale+matmul.

constexpr int C = 64;
constexpr int BN = 128;      // nodes per bucket
constexpr int CHUNK = 4096;  // edges per binning block
constexpr int MAXB = 1024;   // LDS histogram capacity (NB = 782)

// --- 1. per-node histogram ---------------------------------------------------
__global__ __launch_bounds__(256) void hist_kernel(
    const int* __restrict__ tgt, int* __restrict__ counts, int E) {
  int e = blockIdx.x * 256 + threadIdx.x;
  if (e < E) atomicAdd(&counts[tgt[e]], 1);
}

// --- 2. exclusive scan of N node counts (1 block) ---------------------------
__global__ __launch_bounds__(1024) void scan_kernel(
    const int* __restrict__ counts, int* __restrict__ offsets, int N) {
  __shared__ int partials[1024];
  int tid = threadIdx.x;
  int chunk = (N + 1023) / 1024;
  int lo = tid * chunk; if (lo > N) lo = N;
  int hi = lo + chunk;  if (hi > N) hi = N;
  int s = 0;
  for (int i = lo; i < hi; i++) s += counts[i];
  partials[tid] = s;
  __syncthreads();
  for (int off = 1; off < 1024; off <<= 1) {
    int v = partials[tid];
    int a = (tid >= off) ? partials[tid - off] : 0;
    __syncthreads();
    partials[tid] = v + a;
    __syncthreads();
  }
  int run = partials[tid] - s;
  for (int i = lo; i < hi; i++) { offsets[i] = run; run += counts[i]; }
  if (tid == 1023) offsets[N] = partials[1023];
}

// --- 3. bucket cursor init: cursor[b] = offsets[b*BN] -----------------------
__global__ __launch_bounds__(256) void curs_kernel(
    const int* __restrict__ offsets, int* __restrict__ cursor, int NB, int N) {
  int b = blockIdx.x * 256 + threadIdx.x;
  if (b < NB) {
    int i = b * BN; if (i > N) i = N;
    cursor[b] = offsets[i];
  }
}

// --- 4. bin edges into buckets: dense per-(block,bucket) runs ---------------
// rec = src<<7 | (tgt&127). Run writes are dense -> ~1x line amplification.
__global__ __launch_bounds__(256) void bin_kernel(
    const int* __restrict__ src, const int* __restrict__ tgt,
    int* __restrict__ gcursor, unsigned* __restrict__ recs, int E, int NB) {
  __shared__ unsigned rec[CHUNK];
  __shared__ int bkt[CHUNK];
  __shared__ int hist[MAXB];
  __shared__ int gb[MAXB];
  int tid = threadIdx.x;
  int base = blockIdx.x * CHUNK;
  int count = E - base; if (count > CHUNK) count = CHUNK;

  for (int i = tid; i < NB; i += 256) hist[i] = 0;
  __syncthreads();
  for (int i = tid; i < count; i += 256) {
    int s = src[base + i], t = tgt[base + i];
    int b = t >> 7;
    rec[i] = ((unsigned)s << 7) | (unsigned)(t & 127);
    bkt[i] = b;
    atomicAdd(&hist[b], 1);
  }
  __syncthreads();
  for (int i = tid; i < NB; i += 256) {
    int c = hist[i];
    gb[i] = c ? atomicAdd(&gcursor[i], c) : 0;
  }
  __syncthreads();
  for (int i = tid; i < NB; i += 256) hist[i] = 0;
  __syncthreads();
  for (int i = tid; i < count; i += 256) {
    int b = bkt[i];
    int idx = atomicAdd(&hist[b], 1);
    recs[gb[b] + idx] = rec[i];
  }
}

// --- 5. per-bucket counting sort -> exact CSR (dense writes) ----------------
__global__ __launch_bounds__(256) void sort_kernel(
    const unsigned* __restrict__ recs, const int* __restrict__ offsets,
    int* __restrict__ csr_src, int N) {
  __shared__ int lcur[BN];
  int tid = threadIdx.x;
  int b = blockIdx.x;
  int n0 = b * BN;
  int nn = N - n0; if (nn > BN) nn = BN;
  for (int i = tid; i < nn; i += 256) lcur[i] = offsets[n0 + i];
  __syncthreads();
  int beg = offsets[n0];
  int ne = n0 + BN; if (ne > N) ne = N;
  int end = offsets[ne];
  for (int r = beg + tid; r < end; r += 256) {
    unsigned rc = recs[r];
    int pos = atomicAdd(&lcur[rc & 127u], 1);
    csr_src[pos] = (int)(rc >> 7);  // scatter within dense ~20KB block range
  }
}

// --- 6. transposed gather + reduce + scale + matmul -------------------------
// Wave = 16 lanes (float4 channel chunks) x 4 edge slots. One dwordx4 load
// instruction gathers 4 full edge rows (1KB). No shfl/LDS in the load chain.
__global__ __launch_bounds__(256) void gather_kernel(
    const float* __restrict__ x, const int* __restrict__ offsets,
    const int* __restrict__ csr_src, const float* __restrict__ norm,
    const float* __restrict__ W, float* __restrict__ out, int N) {
  int tid = threadIdx.x;
  int lane = tid & 63;
  int wave = tid >> 6;
  int sub = lane & 15;   // float4 chunk: channels 4*sub..4*sub+3
  int grp = lane >> 4;   // edge slot 0..3

  // W column `lane` in 64 VGPRs (coalesced, L2-hot after first wave)
  float wreg[C];
#pragma unroll
  for (int k = 0; k < C; k++) wreg[k] = W[k * C + lane];

  const float4* x4 = (const float4*)x;
  int gw = blockIdx.x * 4 + wave;
  int nwaves = gridDim.x * 4;

  for (int n = gw; n < N; n += nwaves) {
    int beg = offsets[n], end = offsets[n + 1];
    float4 acc;
    if (grp == 0) acc = x4[n * 16 + sub];           // self term once
    else { acc.x = 0.f; acc.y = 0.f; acc.z = 0.f; acc.w = 0.f; }

    for (int e0 = beg; e0 < end; e0 += 16) {        // 16 edges in flight
#pragma unroll
      for (int u = 0; u < 4; u++) {
        int e = e0 + 4 * u + grp;
        if (e < end) {
          int s = csr_src[e];                        // 16B coalesced idx read
          float4 v = x4[s * 16 + sub];               // 1KB: 4 edge rows/instr
          acc.x += v.x; acc.y += v.y; acc.z += v.z; acc.w += v.w;
        }
      }
    }

    // reduce the 4 edge slots (butterfly over lanes 16,32)
    acc.x += __shfl_xor(acc.x, 16, 64); acc.y += __shfl_xor(acc.y, 16, 64);
    acc.z += __shfl_xor(acc.z, 16, 64); acc.w += __shfl_xor(acc.w, 16, 64);
    acc.x += __shfl_xor(acc.x, 32, 64); acc.y += __shfl_xor(acc.y, 32, 64);
    acc.z += __shfl_xor(acc.z, 32, 64); acc.w += __shfl_xor(acc.w, 32, 64);

    float nv = norm[n];
    acc.x *= nv; acc.y *= nv; acc.z *= nv; acc.w *= nv;

    // out[n][lane] = sum_k h[k] * W[k][lane]; h[4*k16+c] lives in lane k16
    float o = 0.0f;
#pragma unroll
    for (int k16 = 0; k16 < 16; k16++) {
      float hx = __shfl(acc.x, k16, 64);
      float hy = __shfl(acc.y, k16, 64);
      float hz = __shfl(acc.z, k16, 64);
      float hw = __shfl(acc.w, k16, 64);
      o = fmaf(hx, wreg[4 * k16 + 0], o);
      o = fmaf(hy, wreg[4 * k16 + 1], o);
      o = fmaf(hz, wreg[4 * k16 + 2], o);
      o = fmaf(hw, wreg[4 * k16 + 3], o);
    }
    out[n * C + lane] = o;
  }
}

extern "C" void kernel_launch(void* const* d_in, const int* in_sizes, int n_in,
                              void* d_out, int out_size, void* d_ws, size_t ws_size,
                              hipStream_t stream) {
  const float* x       = (const float*)d_in[0];
  const int*   sources = (const int*)d_in[1];
  const int*   targets = (const int*)d_in[2];
  const float* norm    = (const float*)d_in[3];
  const float* weight  = (const float*)d_in[4];
  float* out = (float*)d_out;

  int N = in_sizes[0] / C;     // 100000
  int E = in_sizes[1];         // 4000000
  int NB = (N + BN - 1) / BN;  // 782

  // ws: counts[N] | offsets[N+1] | cursor[NB] | csr_src[E]  (~17 MB)
  int* counts  = (int*)d_ws;
  int* offsets = counts + N;
  int* cursor  = offsets + (N + 1);
  int* csr_src = cursor + NB;
  // recs (16 MB) lives in d_out (25.6 MB) -- fully overwritten by gather_kernel
  unsigned* recs = (unsigned*)out;

  hipMemsetAsync(counts, 0, (size_t)N * sizeof(int), stream);

  hist_kernel<<<(E + 255) / 256, 256, 0, stream>>>(targets, counts, E);
  scan_kernel<<<1, 1024, 0, stream>>>(counts, offsets, N);
  curs_kernel<<<(NB + 255) / 256, 256, 0, stream>>>(offsets, cursor, NB, N);
  bin_kernel<<<(E + CHUNK - 1) / CHUNK, 256, 0, stream>>>(sources, targets, cursor, recs, E, NB);
  sort_kernel<<<NB, 256, 0, stream>>>(recs, offsets, csr_src, N);
  gather_kernel<<<4096, 256, 0, stream>>>(x, offsets, csr_src, norm, weight, out, N);
}

// Round 6
// 352.817 us; speedup vs baseline: 5.5340x; 2.0611x over previous
//
#include <hip/hip_runtime.h>

// Conv: out = (norm * (x + segment_sum(x[sources], targets))) @ W
// N = 100000, E = 4000000, C = 64, fp32.
// Pipeline: LDS bucket-hist -> tiny scan -> bin (dense runs) -> fused
// per-bucket sort (per-node offsets computed in LDS, coalesced csr write-out)
// -> bf16 transposed gather (32 edges in flight/wave) + fused scale+matmul.

constexpr int C = 64;
constexpr int BN = 128;      // nodes per bucket
constexpr int CHUNK = 4096;  // edges per hist/bin block
constexpr int MAXB = 1024;   // LDS bucket-hist capacity (NB = 782)
constexpr int CAP = 6144;    // LDS sort staging (max bucket edges; avg 5120)

// --- 1. bucket histogram (LDS, 782 counters) --------------------------------
__global__ __launch_bounds__(256) void bhist_kernel(
    const int* __restrict__ tgt, int* __restrict__ bhist, int E, int NB) {
  __shared__ int h[MAXB];
  for (int i = threadIdx.x; i < NB; i += 256) h[i] = 0;
  __syncthreads();
  int base = blockIdx.x * CHUNK;
  int end = base + CHUNK; if (end > E) end = E;
  for (int i = base + threadIdx.x; i < end; i += 256)
    atomicAdd(&h[tgt[i] >> 7], 1);
  __syncthreads();
  for (int i = threadIdx.x; i < NB; i += 256)
    if (h[i]) atomicAdd(&bhist[i], h[i]);
}

// --- 2. scan of NB bucket counts (1 block); also offsets[N] = E -------------
__global__ __launch_bounds__(256) void bscan_kernel(
    const int* __restrict__ bhist, int* __restrict__ bbase,
    int* __restrict__ cursor, int* __restrict__ offsets, int NB, int N, int E) {
  __shared__ int partials[256];
  int tid = threadIdx.x;
  int per = (NB + 255) / 256;
  int lo = tid * per, hi = lo + per;
  if (lo > NB) lo = NB;
  if (hi > NB) hi = NB;
  int s = 0;
  for (int i = lo; i < hi; i++) s += bhist[i];
  partials[tid] = s;
  __syncthreads();
  for (int off = 1; off < 256; off <<= 1) {
    int v = partials[tid];
    int a = (tid >= off) ? partials[tid - off] : 0;
    __syncthreads();
    partials[tid] = v + a;
    __syncthreads();
  }
  int run = partials[tid] - s;
  for (int i = lo; i < hi; i++) { bbase[i] = run; cursor[i] = run; run += bhist[i]; }
  if (tid == 255) bbase[NB] = partials[255];
  if (tid == 0) offsets[N] = E;
}

// --- 3. bin edges into buckets: dense per-(block,bucket) runs ---------------
__global__ __launch_bounds__(256) void bin_kernel(
    const int* __restrict__ src, const int* __restrict__ tgt,
    int* __restrict__ gcursor, unsigned* __restrict__ recs, int E, int NB) {
  __shared__ unsigned rec[CHUNK];
  __shared__ int bkt[CHUNK];
  __shared__ int hist[MAXB];
  __shared__ int gb[MAXB];
  int tid = threadIdx.x;
  int base = blockIdx.x * CHUNK;
  int count = E - base; if (count > CHUNK) count = CHUNK;

  for (int i = tid; i < NB; i += 256) hist[i] = 0;
  __syncthreads();
  for (int i = tid; i < count; i += 256) {
    int s = src[base + i], t = tgt[base + i];
    int b = t >> 7;
    rec[i] = ((unsigned)s << 7) | (unsigned)(t & 127);
    bkt[i] = b;
    atomicAdd(&hist[b], 1);
  }
  __syncthreads();
  for (int i = tid; i < NB; i += 256) {
    int c = hist[i];
    gb[i] = c ? atomicAdd(&gcursor[i], c) : 0;
  }
  __syncthreads();
  for (int i = tid; i < NB; i += 256) hist[i] = 0;
  __syncthreads();
  for (int i = tid; i < count; i += 256) {
    int b = bkt[i];
    int idx = atomicAdd(&hist[b], 1);
    recs[gb[b] + idx] = rec[i];
  }
}

// --- 4. fused per-bucket sort: per-node offsets + coalesced csr write -------
__global__ __launch_bounds__(256) void sortoff_kernel(
    const unsigned* __restrict__ recs, const int* __restrict__ bbase,
    int* __restrict__ csr_src, int* __restrict__ offsets, int N) {
  __shared__ int cnt[BN];
  __shared__ int pre[BN];
  __shared__ int sorted[CAP];  // 24 KB staging -> coalesced global write
  int tid = threadIdx.x;
  int b = blockIdx.x;
  int n0 = b * BN;
  int nn = N - n0; if (nn > BN) nn = BN;
  int beg = bbase[b], end = bbase[b + 1];
  int m = end - beg;

  if (tid < BN) cnt[tid] = 0;
  __syncthreads();
  for (int r = beg + tid; r < end; r += 256)
    atomicAdd(&cnt[recs[r] & 127u], 1);
  __syncthreads();
  if (tid < BN) pre[tid] = cnt[tid];
  __syncthreads();
  for (int off = 1; off < BN; off <<= 1) {
    int v = (tid < BN) ? pre[tid] : 0;
    int a = (tid >= off && tid < BN) ? pre[tid - off] : 0;
    __syncthreads();
    if (tid < BN) pre[tid] = v + a;
    __syncthreads();
  }
  // exclusive prefix = pre[i] - cnt[i]
  if (tid < nn) offsets[n0 + tid] = beg + pre[tid] - cnt[tid];
  if (tid < BN) cnt[tid] = pre[tid] - cnt[tid];  // bucket-local cursor
  __syncthreads();

  if (m <= CAP) {
    for (int r = beg + tid; r < end; r += 256) {
      unsigned rc = recs[r];
      int p = atomicAdd(&cnt[rc & 127u], 1);
      sorted[p] = (int)(rc >> 7);
    }
    __syncthreads();
    for (int i = tid; i < m; i += 256) csr_src[beg + i] = sorted[i];  // stream
  } else {  // safety fallback (shouldn't trigger at E/NB ~ 5120)
    for (int r = beg + tid; r < end; r += 256) {
      unsigned rc = recs[r];
      int p = atomicAdd(&cnt[rc & 127u], 1);
      csr_src[beg + p] = (int)(rc >> 7);
    }
  }
}

// --- 5. x -> bf16 (RNE) ------------------------------------------------------
__global__ __launch_bounds__(256) void cvt_kernel(
    const float* __restrict__ x, unsigned* __restrict__ xb, int total8) {
  int i = blockIdx.x * 256 + threadIdx.x;  // one thread = 8 floats -> 4 words
  if (i >= total8) return;
  const float4* x4 = (const float4*)x;
  float4 a = x4[i * 2], bq = x4[i * 2 + 1];
  float f[8] = {a.x, a.y, a.z, a.w, bq.x, bq.y, bq.z, bq.w};
  unsigned w[4];
#pragma unroll
  for (int k = 0; k < 4; k++) {
    unsigned u0 = __float_as_uint(f[2 * k]);
    unsigned u1 = __float_as_uint(f[2 * k + 1]);
    u0 = (u0 + 0x7FFFu + ((u0 >> 16) & 1u)) >> 16;
    u1 = (u1 + 0x7FFFu + ((u1 >> 16) & 1u)) >> 16;
    w[k] = u0 | (u1 << 16);
  }
  ((uint4*)xb)[i] = make_uint4(w[0], w[1], w[2], w[3]);
}

// --- 6a. bf16 transposed gather + reduce + scale + matmul -------------------
// Wave = 8 lanes (uint4 = 8 bf16 channels) x 8 edge slots; 32 edges in
// flight per iteration. Self term read from fp32 x (exact).
__global__ __launch_bounds__(256) void gather_bf16_kernel(
    const float* __restrict__ x, const unsigned* __restrict__ xb,
    const int* __restrict__ offsets, const int* __restrict__ csr_src,
    const float* __restrict__ norm, const float* __restrict__ W,
    float* __restrict__ out, int N) {
  int tid = threadIdx.x;
  int lane = tid & 63;
  int wave = tid >> 6;
  int sub = lane & 7;   // channels 8*sub .. 8*sub+7
  int grp = lane >> 3;  // edge slot 0..7

  float wreg[C];
#pragma unroll
  for (int k = 0; k < C; k++) wreg[k] = W[k * C + lane];

  const float4* x4 = (const float4*)x;
  const uint4* xb4 = (const uint4*)xb;  // row = 8 uint4
  int gw = blockIdx.x * 4 + wave;
  int nwaves = gridDim.x * 4;

  for (int n = gw; n < N; n += nwaves) {
    int beg = offsets[n], end = offsets[n + 1];
    float acc[8];
    if (grp == 0) {  // exact fp32 self term
      float4 a = x4[n * 16 + sub * 2], bq = x4[n * 16 + sub * 2 + 1];
      acc[0] = a.x; acc[1] = a.y; acc[2] = a.z; acc[3] = a.w;
      acc[4] = bq.x; acc[5] = bq.y; acc[6] = bq.z; acc[7] = bq.w;
    } else {
#pragma unroll
      for (int j = 0; j < 8; j++) acc[j] = 0.0f;
    }

    for (int e0 = beg; e0 < end; e0 += 32) {
#pragma unroll
      for (int u = 0; u < 4; u++) {
        int e = e0 + 8 * u + grp;
        if (e < end) {
          int s = csr_src[e];
          uint4 v = xb4[s * 8 + sub];  // 128B row per 8-lane group
          acc[0] += __uint_as_float(v.x << 16);
          acc[1] += __uint_as_float(v.x & 0xFFFF0000u);
          acc[2] += __uint_as_float(v.y << 16);
          acc[3] += __uint_as_float(v.y & 0xFFFF0000u);
          acc[4] += __uint_as_float(v.z << 16);
          acc[5] += __uint_as_float(v.z & 0xFFFF0000u);
          acc[6] += __uint_as_float(v.w << 16);
          acc[7] += __uint_as_float(v.w & 0xFFFF0000u);
        }
      }
    }

    // reduce 8 edge slots (butterfly over lanes 8,16,32)
#pragma unroll
    for (int j = 0; j < 8; j++) {
      acc[j] += __shfl_xor(acc[j], 8, 64);
      acc[j] += __shfl_xor(acc[j], 16, 64);
      acc[j] += __shfl_xor(acc[j], 32, 64);
    }

    float nv = norm[n];
#pragma unroll
    for (int j = 0; j < 8; j++) acc[j] *= nv;

    float o = 0.0f;
#pragma unroll
    for (int s = 0; s < 8; s++) {
#pragma unroll
      for (int j = 0; j < 8; j++) {
        o = fmaf(__shfl(acc[j], s, 64), wreg[8 * s + j], o);
      }
    }
    out[n * C + lane] = o;
  }
}

// --- 6b. fp32 fallback gather (R5, proven) ----------------------------------
__global__ __launch_bounds__(256) void gather_f32_kernel(
    const float* __restrict__ x, const int* __restrict__ offsets,
    const int* __restrict__ csr_src, const float* __restrict__ norm,
    const float* __restrict__ W, float* __restrict__ out, int N) {
  int tid = threadIdx.x;
  int lane = tid & 63;
  int wave = tid >> 6;
  int sub = lane & 15;
  int grp = lane >> 4;
  float wreg[C];
#pragma unroll
  for (int k = 0; k < C; k++) wreg[k] = W[k * C + lane];
  const float4* x4 = (const float4*)x;
  int gw = blockIdx.x * 4 + wave;
  int nwaves = gridDim.x * 4;
  for (int n = gw; n < N; n += nwaves) {
    int beg = offsets[n], end = offsets[n + 1];
    float4 acc;
    if (grp == 0) acc = x4[n * 16 + sub];
    else { acc.x = 0.f; acc.y = 0.f; acc.z = 0.f; acc.w = 0.f; }
    for (int e0 = beg; e0 < end; e0 += 16) {
#pragma unroll
      for (int u = 0; u < 4; u++) {
        int e = e0 + 4 * u + grp;
        if (e < end) {
          int s = csr_src[e];
          float4 v = x4[s * 16 + sub];
          acc.x += v.x; acc.y += v.y; acc.z += v.z; acc.w += v.w;
        }
      }
    }
    acc.x += __shfl_xor(acc.x, 16, 64); acc.y += __shfl_xor(acc.y, 16, 64);
    acc.z += __shfl_xor(acc.z, 16, 64); acc.w += __shfl_xor(acc.w, 16, 64);
    acc.x += __shfl_xor(acc.x, 32, 64); acc.y += __shfl_xor(acc.y, 32, 64);
    acc.z += __shfl_xor(acc.z, 32, 64); acc.w += __shfl_xor(acc.w, 32, 64);
    float nv = norm[n];
    acc.x *= nv; acc.y *= nv; acc.z *= nv; acc.w *= nv;
    float o = 0.0f;
#pragma unroll
    for (int k16 = 0; k16 < 16; k16++) {
      o = fmaf(__shfl(acc.x, k16, 64), wreg[4 * k16 + 0], o);
      o = fmaf(__shfl(acc.y, k16, 64), wreg[4 * k16 + 1], o);
      o = fmaf(__shfl(acc.z, k16, 64), wreg[4 * k16 + 2], o);
      o = fmaf(__shfl(acc.w, k16, 64), wreg[4 * k16 + 3], o);
    }
    out[n * C + lane] = o;
  }
}

extern "C" void kernel_launch(void* const* d_in, const int* in_sizes, int n_in,
                              void* d_out, int out_size, void* d_ws, size_t ws_size,
                              hipStream_t stream) {
  const float* x       = (const float*)d_in[0];
  const int*   sources = (const int*)d_in[1];
  const int*   targets = (const int*)d_in[2];
  const float* norm    = (const float*)d_in[3];
  const float* weight  = (const float*)d_in[4];
  float* out = (float*)d_out;

  int N = in_sizes[0] / C;     // 100000
  int E = in_sizes[1];         // 4000000
  int NB = (N + BN - 1) / BN;  // 782

  // ws: bhist[NB] | bbase[NB+1] | cursor[NB] | offsets[N+1] | csr_src[E] | xb
  int* bhist   = (int*)d_ws;
  int* bbase   = bhist + NB;
  int* cursor  = bbase + (NB + 1);
  int* offsets = cursor + NB;
  int* csr_src = offsets + (N + 1);
  unsigned* xb = (unsigned*)(csr_src + E);
  // recs (16 MB) lives in d_out; fully written by bin, dead after sortoff.
  unsigned* recs = (unsigned*)out;

  size_t need_bf16 = (size_t)(3 * NB + 1 + N + 1 + E) * 4 + (size_t)N * C * 2;
  bool use_bf16 = ws_size >= need_bf16;

  hipMemsetAsync(bhist, 0, (size_t)NB * sizeof(int), stream);
  if (use_bf16) {
    int total8 = N * C / 8;
    cvt_kernel<<<(total8 + 255) / 256, 256, 0, stream>>>(x, xb, total8);
  }
  int eb = (E + CHUNK - 1) / CHUNK;  // 977
  bhist_kernel<<<eb, 256, 0, stream>>>(targets, bhist, E, NB);
  bscan_kernel<<<1, 256, 0, stream>>>(bhist, bbase, cursor, offsets, NB, N, E);
  bin_kernel<<<eb, 256, 0, stream>>>(sources, targets, cursor, recs, E, NB);
  sortoff_kernel<<<NB, 256, 0, stream>>>(recs, bbase, csr_src, offsets, N);
  if (use_bf16) {
    gather_bf16_kernel<<<4096, 256, 0, stream>>>(x, xb, offsets, csr_src, norm, weight, out, N);
  } else {
    gather_f32_kernel<<<4096, 256, 0, stream>>>(x, offsets, csr_src, norm, weight, out, N);
  }
}